// Round 11
// baseline (251.217 us; speedup 1.0000x reference)
//
#include <hip/hip_runtime.h>
#include <math.h>

#define W    3072
#define HH   3072
#define HOUT 3060       // HH - 12 (valid conv output for 13x13 kernel)
#define TW   64         // output cols per block
#define TH   56         // output rows per block (8 waves x 7 rows)
#define RW   7          // rows per wave
#define NW   8          // waves per block (512 threads)
#define XR   68         // xt rows = TH + 12
#define XTS  76         // xt col stride
#define VTS  77         // vt col stride: H bank = (13*r8+8*cg)%32 -> exactly
                        // 2 lanes/bank (free); V writes lane-consecutive
#define VTW  (RW*VTS)   // per-wave vt words = 539
#define GX   48
#define GY   55         // 55*56 = 3080 >= 3072 (masked)
#define GZ   2
#define NBLK (GX*GY*GZ)
#define NTHR (NBLK*512)
#define NSLOT 64        // accumulator slots, each (slot,j) on its own 64B line
#define NSTG ((XR*19+511)/512)   // staging iterations per thread = 3

struct HessTaps { float a[13]; float bb[13]; float m[13]; float n[13]; };

// ---- module-global accumulator state: zero-init at load, SELF-RESETTING
// (finalize re-zeroes after reading), so no memset dispatch is needed.
// LESSONS:
//  * rounds 0-4: atomics to ONE 64B line serialize (~13ns each) -> slot-spread
//    across 64 lines (round 5: 798 -> 123us).
//  * rounds 7-8: ANY in-kernel completion protocol (threadfence + returning
//    ticket atomic + final barrier) costs ~150us of CU-residency hold time.
//    Kernel-boundary stream ordering is the free release/acquire (round 9).
__device__ double g_slots[NSLOT * 32];   // (slot,j) at byte slot*256 + j*64

// ---- Hessian + TV + folded gf/mse, both images via gridDim.z ---------------
// 64x56 tile, 8 waves x 7 rows, 512 threads, wave-local V->H (vt wave-
// private), scalar f32 FMAs (v_pk_fma_f32 is half-rate on gfx950: fp32 peak
// == scalar FMA rate, verified rounds 1-2). Round-11 changes vs the 104us
// round-10 body:
//  * 512-thread blocks, RW=7: LDS 38016 -> 4 blocks/CU x 8 waves = 32
//    waves/CU = 100% occupancy ceiling (was 75%; measured 58% @ 75% VALUBusy
//    -> occupancy still the binding lever). __launch_bounds__(512,8), VGPR
//    cap 64 (body used 40 at RW=9; WRITE_SIZE is the spill tripwire).
//  * H remap to (r8=ln>>3, cg=ln&7), 8 cols/lane, r8<7: bank =
//    (13*r8+8*cg)%32 -> exactly 2 lanes/bank = FREE (round-10's 10-wide
//    cg was a 4.66M-conflict mistake; this restores ~0 conflicts).
//  * T window preloaded into 3 static float4 regs BEFORE barrier 1; d-update
//    is pure LDS/VALU. gf/mse loads (now 1 guarded pair) before barrier 1.
// LDS: xt 68*76*4=20672 + vt 8*539*4=17248 + red 96 = 38016 -> 38400 rounded.
__global__ __launch_bounds__(512, 8) void hess_kernel(const float* __restrict__ Gnn,
                                                      const float* __restrict__ Lr,
                                                      const float* __restrict__ T,
                                                      const float* __restrict__ Xr,
                                                      const float* __restrict__ St,
                                                      const float* __restrict__ Mp,
                                                      HessTaps tp) {
  __shared__ float xt[XR * XTS];
  __shared__ float vt[NW * VTW];
  __shared__ float red[NW][3];
  const float* img = (blockIdx.z == 0) ? Gnn : Lr;
  int oy = blockIdx.y * TH, ox = blockIdx.x * TW;
  int t = threadIdx.x;
  int wv = t >> 6, ln = t & 63;    // wave id 0..7, lane 0..63
  int r0 = wv * RW;

  // load xt (68 rows x 76 cols) as aligned float4 with edge masking
  for (int idx = t; idx < XR * 19; idx += 512) {
    int r = idx / 19, g = idx - r * 19;
    int gr = oy + r, gc = ox + 4 * g;
    float4 v = {0.f, 0.f, 0.f, 0.f};
    if (gr < HH) {
      const float* p = &img[(size_t)gr * W + gc];
      if (gc + 3 < W) v = *(const float4*)p;
      else {
        if (gc < W)     v.x = p[0];
        if (gc + 1 < W) v.y = p[1];
        if (gc + 2 < W) v.z = p[2];
      }
    }
    *(float4*)&xt[r * XTS + 4 * g] = v;
  }

  // ---- preload the T window for the d-update (static 3x float4, masked);
  // latency hides under term-1 compute instead of stalling at barrier 2.
  float4 tr4[NSTG];
  #pragma unroll
  for (int k = 0; k < NSTG; ++k) {
    int idx = t + 512 * k;
    float4 v = {0.f, 0.f, 0.f, 0.f};
    if (idx < XR * 19) {
      int r = idx / 19, g = idx - r * 19;
      int gr = oy + r, gc = ox + 4 * g;
      if (gr < HH) {
        const float* p = &T[(size_t)gr * W + gc];
        if (gc + 3 < W) v = *(const float4*)p;
        else {
          if (gc < W)     v.x = p[0];
          if (gc + 1 < W) v.y = p[1];
          if (gc + 2 < W) v.z = p[2];
        }
      }
    }
    tr4[k] = v;
  }

  // ---- issue gf/mse global loads now; latency hides under the whole conv.
  // NTHR (2.70M threads) > n4 (2.36M float4s) -> ONE guarded pair suffices.
  int bid = (blockIdx.z * GY + blockIdx.y) * GX + blockIdx.x;
  int i0 = bid * 512 + t;
  const int n4 = (W * HH) / 4;
  float4 ga0 = {0.f, 0.f, 0.f, 0.f}, gb0 = ga0;
  bool has0 = (i0 < n4);
  if (has0) { ga0 = ((const float4*)Xr)[i0]; gb0 = ((const float4*)St)[i0]; }
  float mT = 0.f, mG = 0.f, mM = 0.f;
  bool hasm = (i0 < 384 * 384);
  if (hasm) {
    int si = i0 / 384, sj = i0 - si * 384;
    int id = si * 8 * W + sj * 8;
    mT = T[id]; mG = Gnn[id]; mM = Mp[id];
  }
  __builtin_amdgcn_sched_barrier(0);

  __syncthreads();     // barrier 1: xt staged

  float tvl = 0.f;   // TV accumulator
  float hl  = 0.f;   // Hessian accumulator

  // TV Dx term on x: |x(r,c) - x(r,c+1)|  (lanes contiguous -> free)
  {
    int gc = ox + ln;
    if (gc < W - 1) {
      #pragma unroll
      for (int i = 0; i < RW; ++i) {
        int r = r0 + i;
        if (oy + r < HH)
          tvl += fabsf(xt[r * XTS + ln] - xt[r * XTS + ln + 1]);
      }
    }
  }

  // ---- V pass: main 64 cols (all lanes) + dense halo (12x7=84 outputs,
  // <=2 per lane). Per-output tap order u-ascending -> bitwise identical.
  #define VPASS(TAP)                                                        \
    {                                                                       \
      /* main: lane = col ln; 7 sliding accumulators over 19-row window */  \
      float oA[RW];                                                         \
      _Pragma("unroll")                                                     \
      for (int i = 0; i < RW; ++i) oA[i] = 0.f;                             \
      _Pragma("unroll")                                                     \
      for (int u = 0; u < RW + 12; ++u) {                                   \
        float xA = xt[(r0 + u) * XTS + ln];                                 \
        _Pragma("unroll")                                                   \
        for (int i = 0; i < RW; ++i) {                                      \
          int kk = u - i;                                                   \
          if (kk >= 0 && kk <= 12) oA[i] = fmaf((TAP)[kk], xA, oA[i]);      \
        }                                                                   \
      }                                                                     \
      float* vw = &vt[wv * VTW + ln];                                       \
      _Pragma("unroll")                                                     \
      for (int i = 0; i < RW; ++i) vw[i * VTS] = oA[i];                     \
      /* halo: 12 cols x 7 rows = 84 outputs, <=2 per lane */               \
      _Pragma("unroll")                                                     \
      for (int k = 0; k < 2; ++k) {                                         \
        int o = ln + 64 * k;                                                \
        if (o < 12 * RW) {                                                  \
          int row = o / 12, hc = o - row * 12;                              \
          const float* xp = &xt[(r0 + row) * XTS + 64 + hc];                \
          float s = 0.f;                                                    \
          _Pragma("unroll")                                                 \
          for (int u = 0; u < 13; ++u) s = fmaf((TAP)[u], xp[u * XTS], s);  \
          vt[wv * VTW + row * VTS + 64 + hc] = s;                           \
        }                                                                   \
      }                                                                     \
    }

  // ---- H pass: lane = (r8 = ln>>3, cg = ln&7), r8 < 7; 20 scalar sliding
  // reads at bank (13*r8+8*cg)%32 -> exactly 2 lanes/bank (FREE); 8 outputs
  // at cols cg*8..+7. Tap order j-ascending -> bitwise identical.
  #define HSECOND(TAP, WGT)                                                 \
    {                                                                       \
      int r8 = ln >> 3, cg = ln & 7;                                        \
      if (r8 < RW) {                                                        \
        const float* vrow = &vt[wv * VTW + r8 * VTS + cg * 8];              \
        float o_[8];                                                        \
        _Pragma("unroll")                                                   \
        for (int jj = 0; jj < 8; ++jj) o_[jj] = 0.f;                        \
        _Pragma("unroll")                                                   \
        for (int j = 0; j < 20; ++j) {                                      \
          float v = vrow[j];                                                \
          _Pragma("unroll")                                                 \
          for (int jj = 0; jj < 8; ++jj) {                                  \
            int kk = j - jj;                                                \
            if (kk >= 0 && kk <= 12) o_[jj] = fmaf((TAP)[kk], v, o_[jj]);   \
          }                                                                 \
        }                                                                   \
        int gr = oy + r0 + r8;                                              \
        int gc0 = ox + cg * 8;                                              \
        float wr = (gr < HOUT) ? (WGT) : 0.f;                               \
        _Pragma("unroll")                                                   \
        for (int jj = 0; jj < 8; ++jj) {                                    \
          float m_ = (gc0 + jj < HOUT) ? wr : 0.f;                          \
          hl = fmaf(m_, fabsf(o_[jj]), hl);                                 \
        }                                                                   \
      }                                                                     \
    }

  // term 1: conv(x, Gxx) = vert bb, horiz a   (vt is wave-private: no barrier)
  VPASS(tp.bb);
  HSECOND(tp.a, 1.0f);

  // d = x - target (in place), using the preloaded T registers: pure
  // LDS/VALU between the barriers -- no global-load bubble.
  __syncthreads();     // barrier 2
  #pragma unroll
  for (int k = 0; k < NSTG; ++k) {
    int idx = t + 512 * k;
    if (idx < XR * 19) {
      int r = idx / 19, g = idx - r * 19;
      float4 cur = *(float4*)&xt[r * XTS + 4 * g];
      cur.x -= tr4[k].x; cur.y -= tr4[k].y;
      cur.z -= tr4[k].z; cur.w -= tr4[k].w;
      *(float4*)&xt[r * XTS + 4 * g] = cur;
    }
  }
  __syncthreads();     // barrier 3

  // TV Dy term on d: |d(r,c) - d(r+1,c)|, r < HH-1
  {
    int gc = ox + ln;
    if (gc < W) {
      #pragma unroll
      for (int i = 0; i < RW; ++i) {
        int r = r0 + i;
        if (oy + r < HH - 1)
          tvl += fabsf(xt[r * XTS + ln] - xt[(r + 1) * XTS + ln]);
      }
    }
  }

  // term 2: conv(d, Gyy) = vert a, horiz bb
  VPASS(tp.a);
  HSECOND(tp.bb, 1.0f);

  // term 3: conv(d, Gxy) = vert m, horiz n, weight 2 (isotropic)
  VPASS(tp.m);
  HSECOND(tp.n, 2.0f);

  // folded gf term (gf(x,x)==x exactly -> sum|st-x|) + sampled L1*map;
  // operands loaded before barrier 1, latency hidden under the conv.
  float gm = 0.f;
  if (has0)
    gm = fabsf(gb0.x - ga0.x) + fabsf(gb0.y - ga0.y)
       + fabsf(gb0.z - ga0.z) + fabsf(gb0.w - ga0.w);
  if (hasm) gm += fabsf(mT - mG) * mM;

  // ---- fused block reduction: one barrier, then 3 FIRE-AND-FORGET slot
  // atomics by thread 0 and IMMEDIATE exit (no fence, no ticket, no tail).
  #pragma unroll
  for (int o = 32; o > 0; o >>= 1) {
    gm  += __shfl_down(gm,  o, 64);
    tvl += __shfl_down(tvl, o, 64);
    hl  += __shfl_down(hl,  o, 64);
  }
  if (ln == 0) { red[wv][0] = gm; red[wv][1] = tvl; red[wv][2] = hl; }
  __syncthreads();     // barrier 4 (final)
  if (t == 0) {
    float s0 = 0.f, s1 = 0.f, s2 = 0.f;
    #pragma unroll
    for (int w = 0; w < NW; ++w) {
      s0 += red[w][0]; s1 += red[w][1]; s2 += red[w][2];
    }
    int slot = bid & (NSLOT - 1);
    double* base = g_slots + (size_t)slot * 32;
    unsafeAtomicAdd(base,      (double)s0);
    unsafeAtomicAdd(base + 8,  (double)s1);
    unsafeAtomicAdd(base + 16, (double)s2);
  }
}

// ---- combine (1 wave): plain loads (kernel boundary = acquire), re-zero the
// slots for the next launch/replay (kernel end = release), write the result.
__global__ __launch_bounds__(64) void finalize_kernel(float* __restrict__ out) {
  int t = threadIdx.x;             // lane t owns slot t
  double* b = g_slots + (size_t)t * 32;
  double s0 = b[0];  b[0]  = 0.0;
  double s1 = b[8];  b[8]  = 0.0;
  double s3 = b[16]; b[16] = 0.0;
  #pragma unroll
  for (int o = 32; o > 0; o >>= 1) {
    s0 += __shfl_down(s0, o, 64);
    s1 += __shfl_down(s1, o, 64);
    s3 += __shfl_down(s3, o, 64);
  }
  if (t == 0) out[0] = (float)(s0 + 0.1 * s1 + 0.5 * s3);
}

extern "C" void kernel_launch(void* const* d_in, const int* in_sizes, int n_in,
                              void* d_out, int out_size, void* d_ws, size_t ws_size,
                              hipStream_t stream) {
  const float* xraw = (const float*)d_in[0];   // outputGNNraw
  const float* gnn  = (const float*)d_in[1];   // outputGNN
  const float* lr   = (const float*)d_in[2];   // outputLR
  const float* st   = (const float*)d_in[3];   // smoothedTarget
  const float* tg   = (const float*)d_in[4];   // targets
  const float* mp   = (const float*)d_in[5];   // map
  float* out = (float*)d_out;

  // separable Hessian-of-Gaussian taps (sigma=1, t = -6..6):
  //   Gxx[i,j] = bb(i)*a(j); Gyy[i,j] = a(i)*bb(j); Gxy[i,j] = m(i)*n(j)
  HessTaps tp;
  const double PI2 = 6.283185307179586476925287;
  for (int k = 0; k < 13; ++k) {
    double tt = (double)(k - 6);
    double g = exp(-0.5 * tt * tt);
    tp.a[k]  = (float)((tt * tt - 1.0) * g / PI2);
    tp.bb[k] = (float)g;
    tp.m[k]  = (float)(tt * g / PI2);
    tp.n[k]  = (float)(tt * g);
  }

  // TWO dispatches (no memset: globals are self-resetting):
  // grid 48 x-tiles * 55 y-tiles (55*56=3080 >= 3072, masked) * {GNN, LR}
  hess_kernel<<<dim3(GX, GY, GZ), 512, 0, stream>>>(gnn, lr, tg, xraw, st, mp,
                                                    tp);
  finalize_kernel<<<1, 64, 0, stream>>>(out);
}